// Round 2
// baseline (209.967 us; speedup 1.0000x reference)
//
#include <hip/hip_runtime.h>
#include <hip/hip_bf16.h>
#include <stdint.h>

#define B_SZ  8192
#define IN_SZ 1024
#define H_SZ  1024
#define K_BR  4
#define BR_SZ 512
#define J_SZ  2048   // IN + H (GEMM K dim)

#define FIX_THR 0.25f        // flag |0.5*v-1| < THR for exact fp32 recompute
#define MAXFIX  (1 << 20)    // 1M entries, 4MB

typedef __attribute__((ext_vector_type(8))) short  short8;   // 8 bf16 = 4 VGPRs
typedef __attribute__((ext_vector_type(4))) float  f32x4;

__device__ __forceinline__ unsigned short f2bf(float f) {
    union { __hip_bfloat16 b; unsigned short u; } cv;
    cv.b = __float2bfloat16(f);
    return cv.u;
}

__device__ __forceinline__ void gl_lds16(const void* g, void* l) {
    __builtin_amdgcn_global_load_lds(
        (const __attribute__((address_space(1))) void*)g,
        (__attribute__((address_space(3))) void*)l, 16, 0, 0);
}

__global__ void zero_cnt(int* cnt) { if (threadIdx.x == 0) *cnt = 0; }

// ---- prep 1: alpha = sigmoid(taus), biasw[h] = sum_k (1-alpha)*b[k,h] ----
__global__ void prep_alpha(const float* __restrict__ taus, const float* __restrict__ bvec,
                           float* __restrict__ alpha, float* __restrict__ biasw) {
    int h = blockIdx.x * blockDim.x + threadIdx.x;
    if (h >= H_SZ) return;
    float bsum = 0.f;
    for (int k = 0; k < K_BR; ++k) {
        float a = 1.f / (1.f + expf(-taus[k * H_SZ + h]));
        alpha[k * H_SZ + h] = a;
        bsum += (1.f - a) * bvec[k * H_SZ + h];
    }
    biasw[h] = bsum;
}

// ---- prep 2: Wt[h][k*512+i] = (1-alpha[k,h]) * W[k,h,i]  (bf16, B^T layout) ----
__global__ void build_wt(const float* __restrict__ W, const float* __restrict__ alpha,
                         unsigned short* __restrict__ Wt) {
    int t = blockIdx.x * 256 + threadIdx.x;
    int e0 = t * 8;
    if (e0 >= H_SZ * J_SZ) return;
    int h  = e0 >> 11;
    int j0 = e0 & 2047;
    int k  = j0 >> 9;
    int i0 = j0 & 511;
    float s = 1.f - alpha[k * H_SZ + h];
    const float* src = W + ((size_t)(k * H_SZ + h)) * BR_SZ + i0;
    union { short8 v; unsigned short u[8]; } o;
    #pragma unroll
    for (int q = 0; q < 8; ++q) o.u[q] = f2bf(s * src[q]);
    *(short8*)(Wt + (size_t)h * J_SZ + j0) = o.v;
}

// ---- prep 3: Xb[b][j] = bf16(concat(input_t, hidden)[b][j]) ----
__global__ void build_xb(const float* __restrict__ inp, const float* __restrict__ hid,
                         unsigned short* __restrict__ Xb) {
    int t = blockIdx.x * 256 + threadIdx.x;
    long long e0 = (long long)t * 8;
    if (e0 >= (long long)B_SZ * J_SZ) return;
    int b  = (int)(e0 >> 11);
    int j0 = (int)(e0 & 2047);
    const float* src = (j0 < IN_SZ) ? (inp + (size_t)b * IN_SZ + j0)
                                    : (hid + (size_t)b * H_SZ + (j0 - IN_SZ));
    union { short8 v; unsigned short u[8]; } o;
    #pragma unroll
    for (int q = 0; q < 8; ++q) o.u[q] = f2bf(src[q]);
    *(short8*)(Xb + (size_t)b * J_SZ + j0) = o.v;
}

// ---- main: 128x128 bf16 MFMA GEMM (m97 structure) + fused LIF/spike epilogue ----
__global__ void gemm_spike(const unsigned short* __restrict__ Xb,
                           const unsigned short* __restrict__ Wt,
                           const float* __restrict__ alpha,
                           const float* __restrict__ biasw,
                           const float* __restrict__ bs,
                           float* __restrict__ out,
                           int* __restrict__ cnt,
                           int* __restrict__ list) {
    __shared__ unsigned short As[128 * 32];   // [m][k] 8KB
    __shared__ unsigned short Bs[128 * 32];   // [n][k] 8KB (B^T tile)
    const int tid  = threadIdx.x;
    const int wid  = tid >> 6;
    const int lane = tid & 63;
    const int bm0  = blockIdx.x * 128;
    const int bn0  = blockIdx.y * 128;
    const int wm   = (wid >> 1) * 64;
    const int wn   = (wid & 1) * 64;

    f32x4 acc[4][4];
    #pragma unroll
    for (int mi = 0; mi < 4; ++mi)
        #pragma unroll
        for (int ni = 0; ni < 4; ++ni)
            acc[mi][ni] = (f32x4){0.f, 0.f, 0.f, 0.f};

    const int ko = (lane >> 4) * 8;   // k offset of this lane's fragment
    const int rm = lane & 15;         // row/col within 16

    for (int kt = 0; kt < J_SZ; kt += 32) {
        #pragma unroll
        for (int p = 0; p < 2; ++p) {
            int o  = p * 4096 + wid * 1024 + lane * 16;  // byte off in 8KB tile
            int r  = o >> 6;
            int cb = o & 63;
            const unsigned short* gA = Xb + (size_t)(bm0 + r) * J_SZ + kt + (cb >> 1);
            const unsigned short* gB = Wt + (size_t)(bn0 + r) * J_SZ + kt + (cb >> 1);
            gl_lds16(gA, (char*)As + p * 4096 + wid * 1024);
            gl_lds16(gB, (char*)Bs + p * 4096 + wid * 1024);
        }
        __syncthreads();

        short8 af[4], bf[4];
        #pragma unroll
        for (int mi = 0; mi < 4; ++mi)
            af[mi] = *(const short8*)(As + (wm + mi * 16 + rm) * 32 + ko);
        #pragma unroll
        for (int ni = 0; ni < 4; ++ni)
            bf[ni] = *(const short8*)(Bs + (wn + ni * 16 + rm) * 32 + ko);
        #pragma unroll
        for (int mi = 0; mi < 4; ++mi)
            #pragma unroll
            for (int ni = 0; ni < 4; ++ni)
                acc[mi][ni] = __builtin_amdgcn_mfma_f32_16x16x32_bf16(
                                  af[mi], bf[ni], acc[mi][ni], 0, 0, 0);
        __syncthreads();
    }

    // epilogue: + biasw + sum_k alpha*branch_states, /tau, heaviside, flag borderline
    const int rr = (lane >> 4) * 4;   // C/D row base
    const int cn = lane & 15;         // C/D col
    #pragma unroll
    for (int ni = 0; ni < 4; ++ni) {
        int col = bn0 + wn + ni * 16 + cn;
        float bw = biasw[col];
        float a0 = alpha[0 * H_SZ + col], a1 = alpha[1 * H_SZ + col];
        float a2 = alpha[2 * H_SZ + col], a3 = alpha[3 * H_SZ + col];
        #pragma unroll
        for (int mi = 0; mi < 4; ++mi) {
            #pragma unroll
            for (int r = 0; r < 4; ++r) {
                int row = bm0 + wm + mi * 16 + rr + r;
                const float* bsp = bs + (size_t)row * (K_BR * H_SZ) + col;
                float v = acc[mi][ni][r] + bw
                        + a0 * bsp[0]        + a1 * bsp[H_SZ]
                        + a2 * bsp[2 * H_SZ] + a3 * bsp[3 * H_SZ];
                float sv = 0.5f * v - 1.0f;
                out[(size_t)row * H_SZ + col] = (sv >= 0.f) ? 1.0f : 0.0f;
                if (fabsf(sv) < FIX_THR) {
                    int slot = atomicAdd(cnt, 1);
                    if (slot < MAXFIX) list[slot] = row * H_SZ + col;
                }
            }
        }
    }
}

// ---- fixup: exact fp32 recompute of flagged (row,col), one wave each ----
__global__ void fixup(const float* __restrict__ inp, const float* __restrict__ hid,
                      const float* __restrict__ bs, const float* __restrict__ W,
                      const float* __restrict__ bvec, const float* __restrict__ alpha,
                      const int* __restrict__ cnt, const int* __restrict__ list,
                      float* __restrict__ out) {
    int wave  = (blockIdx.x * blockDim.x + threadIdx.x) >> 6;
    int lane  = threadIdx.x & 63;
    int nwave = gridDim.x * (blockDim.x >> 6);
    int n = *cnt;
    if (n > MAXFIX) n = MAXFIX;
    for (int it = wave; it < n; it += nwave) {
        int idx = list[it];
        int row = idx >> 10, col = idx & 1023;
        float a[K_BR];
        #pragma unroll
        for (int k = 0; k < K_BR; ++k) a[k] = alpha[k * H_SZ + col];
        float acc = 0.f;
        for (int j = lane; j < J_SZ; j += 64) {
            int k = j >> 9, i = j & 511;
            float x = (j < IN_SZ) ? inp[(size_t)row * IN_SZ + j]
                                  : hid[(size_t)row * H_SZ + (j - IN_SZ)];
            float w = W[((size_t)(k * H_SZ + col)) * BR_SZ + i];
            acc += (1.f - a[k]) * x * w;
        }
        #pragma unroll
        for (int off = 32; off; off >>= 1) acc += __shfl_xor(acc, off, 64);
        if (lane == 0) {
            float tot = acc;
            #pragma unroll
            for (int k = 0; k < K_BR; ++k)
                tot += (1.f - a[k]) * bvec[k * H_SZ + col]
                     + a[k] * bs[(size_t)row * (K_BR * H_SZ) + k * H_SZ + col];
            out[(size_t)row * H_SZ + col] = (0.5f * tot - 1.f >= 0.f) ? 1.f : 0.f;
        }
    }
}

// ---- fallback if workspace too small: direct fp32 (slow but correct) ----
__global__ void naive_kernel(const float* __restrict__ inp, const float* __restrict__ hid,
                             const float* __restrict__ bs, const float* __restrict__ W,
                             const float* __restrict__ bvec, const float* __restrict__ taus,
                             float* __restrict__ out) {
    int idx = blockIdx.x * 256 + threadIdx.x;
    if (idx >= B_SZ * H_SZ) return;
    int b = idx >> 10, h = idx & 1023;
    float tot = 0.f;
    for (int k = 0; k < K_BR; ++k) {
        const float* x = (k < 2) ? (inp + (size_t)b * IN_SZ + k * BR_SZ)
                                 : (hid + (size_t)b * H_SZ + (k - 2) * BR_SZ);
        const float* w = W + ((size_t)k * H_SZ + h) * BR_SZ;
        float d = 0.f;
        for (int i = 0; i < BR_SZ; ++i) d += x[i] * w[i];
        d += bvec[k * H_SZ + h];
        float a = 1.f / (1.f + expf(-taus[k * H_SZ + h]));
        tot += a * bs[(size_t)b * (K_BR * H_SZ) + k * H_SZ + h] + (1.f - a) * d;
    }
    out[idx] = (0.5f * tot - 1.f >= 0.f) ? 1.f : 0.f;
}

extern "C" void kernel_launch(void* const* d_in, const int* in_sizes, int n_in,
                              void* d_out, int out_size, void* d_ws, size_t ws_size,
                              hipStream_t stream) {
    const float* input_t = (const float*)d_in[0];
    const float* hidden  = (const float*)d_in[1];
    const float* bs      = (const float*)d_in[2];
    const float* W       = (const float*)d_in[3];
    const float* bvec    = (const float*)d_in[4];
    const float* taus    = (const float*)d_in[5];
    float* out = (float*)d_out;

    const size_t ALPHA_OFF = 0;
    const size_t BIAS_OFF  = 16 * 1024;
    const size_t CNT_OFF   = 32 * 1024;
    const size_t LIST_OFF  = 48 * 1024;
    const size_t WT_OFF    = LIST_OFF + (size_t)MAXFIX * 4;      // +4MB
    const size_t XB_OFF    = WT_OFF + (size_t)H_SZ * J_SZ * 2;   // +4MB
    const size_t WS_NEED   = XB_OFF + (size_t)B_SZ * J_SZ * 2;   // +32MB

    if (ws_size < WS_NEED) {
        naive_kernel<<<(B_SZ * H_SZ + 255) / 256, 256, 0, stream>>>(
            input_t, hidden, bs, W, bvec, taus, out);
        return;
    }

    float*          alphaw = (float*)((char*)d_ws + ALPHA_OFF);
    float*          biasw  = (float*)((char*)d_ws + BIAS_OFF);
    int*            cnt    = (int*)((char*)d_ws + CNT_OFF);
    int*            list   = (int*)((char*)d_ws + LIST_OFF);
    unsigned short* Wt     = (unsigned short*)((char*)d_ws + WT_OFF);
    unsigned short* Xb     = (unsigned short*)((char*)d_ws + XB_OFF);

    zero_cnt<<<1, 64, 0, stream>>>(cnt);
    prep_alpha<<<4, 256, 0, stream>>>(taus, bvec, alphaw, biasw);
    build_wt<<<(H_SZ * J_SZ / 8 + 255) / 256, 256, 0, stream>>>(W, alphaw, Wt);
    build_xb<<<(B_SZ * J_SZ / 8 + 255) / 256, 256, 0, stream>>>(input_t, hidden, Xb);
    gemm_spike<<<dim3(B_SZ / 128, H_SZ / 128), 256, 0, stream>>>(
        Xb, Wt, alphaw, biasw, bs, out, cnt, list);
    fixup<<<256, 256, 0, stream>>>(input_t, hidden, bs, W, bvec, alphaw, cnt, list, out);
}